// Round 6
// baseline (264.020 us; speedup 1.0000x reference)
//
#include <hip/hip_runtime.h>
#include <cstdint>
#include <cstddef>

#define Bb 4
#define Tt 2048
#define Ssz 2048
#define Cc 256
#define Ee 512
#define Hh 8

typedef short bf8 __attribute__((ext_vector_type(8)));
typedef float f4 __attribute__((ext_vector_type(4)));

__device__ __forceinline__ unsigned short f2bf(float x) {
  unsigned int u = __float_as_uint(x);
  u += 0x7fffu + ((u >> 16) & 1u);
  return (unsigned short)(u >> 16);
}

__device__ __forceinline__ bf8 cvt8(float4 a, float4 b) {
  bf8 r;
  r[0] = (short)f2bf(a.x); r[1] = (short)f2bf(a.y);
  r[2] = (short)f2bf(a.z); r[3] = (short)f2bf(a.w);
  r[4] = (short)f2bf(b.x); r[5] = (short)f2bf(b.y);
  r[6] = (short)f2bf(b.z); r[7] = (short)f2bf(b.w);
  return r;
}

// ---------------- prep: weight casts + wqin GEMM + bqin + packmask ----------------
// bid<2048: packmask; <2560: wk/wv cast; <2688: wo cast; <2720: wqin; <2736: bqin
__global__ __launch_bounds__(256) void prep(const int* __restrict__ mask,
                                            const float* __restrict__ w_in,
                                            const float* __restrict__ b_in,
                                            const float* __restrict__ wq,
                                            const float* __restrict__ bq,
                                            const float* __restrict__ wk,
                                            const float* __restrict__ wv,
                                            const float* __restrict__ wo,
                                            unsigned int* __restrict__ mp,
                                            unsigned short* __restrict__ wkvb,
                                            unsigned short* __restrict__ wob,
                                            unsigned short* __restrict__ wqin,
                                            float* __restrict__ bqinb, float qsc) {
  __shared__ unsigned short sh[128][72];
  const int bid = blockIdx.x, tid = threadIdx.x;
  if (bid < 2048) {
    int i = bid * 256 + tid;
    const int4* src = (const int4*)mask + (size_t)i * 8;
    unsigned int w = 0;
#pragma unroll
    for (int k = 0; k < 8; k++) {
      int4 v = src[k];
      w |= (unsigned int)(v.x != 0) << (k * 4);
      w |= (unsigned int)(v.y != 0) << (k * 4 + 1);
      w |= (unsigned int)(v.z != 0) << (k * 4 + 2);
      w |= (unsigned int)(v.w != 0) << (k * 4 + 3);
    }
    mp[i] = w;
  } else if (bid < 2560) {
    int i = (bid - 2048) * 256 + tid;  // 0..131071
    const float* s = (i < 65536) ? wk : wv;
    int off = (i < 65536) ? i : i - 65536;
    float4 v = ((const float4*)s)[off];
    ushort4 o;
    o.x = f2bf(v.x); o.y = f2bf(v.y); o.z = f2bf(v.z); o.w = f2bf(v.w);
    ((ushort4*)wkvb)[i] = o;
  } else if (bid < 2688) {
    int i = (bid - 2560) * 256 + tid;  // 0..32767
    float4 v = ((const float4*)wo)[i];
    ushort4 o;
    o.x = f2bf(v.x); o.y = f2bf(v.y); o.z = f2bf(v.z); o.w = f2bf(v.w);
    ((ushort4*)wob)[i] = o;
  } else if (bid < 2720) {
    // wqin[512,256] = (qsc*wq)[512,512] . w_in[512,256]
    const int idx = bid - 2688;
    const int m0 = (idx & 7) * 64, n0 = (idx >> 3) * 64;
    unsigned short (*As)[72] = (unsigned short (*)[72]) & sh[0][0];
    unsigned short (*Bs)[72] = (unsigned short (*)[72]) & sh[64][0];
    const int wave = tid >> 6, lane = tid & 63;
    const int lrow = lane & 15, quad = lane >> 4;
    const int wm = (wave >> 1) * 32, wn = (wave & 1) * 32;
    const int arow = tid >> 3, ac = tid & 7;
    f4 acc[2][2];
#pragma unroll
    for (int i = 0; i < 2; i++)
#pragma unroll
      for (int j = 0; j < 2; j++) {
        f4 z = {0.f, 0.f, 0.f, 0.f};
        acc[i][j] = z;
      }
    for (int kt = 0; kt < 8; kt++) {
#pragma unroll
      for (int i = 0; i < 2; i++) {
        int row = arow + i * 32;
        const float* src = wq + (size_t)(m0 + row) * Ee + kt * 64 + ac * 8;
        float4 v0 = *(const float4*)src, v1 = *(const float4*)(src + 4);
        bf8 av;
        av[0] = (short)f2bf(v0.x * qsc); av[1] = (short)f2bf(v0.y * qsc);
        av[2] = (short)f2bf(v0.z * qsc); av[3] = (short)f2bf(v0.w * qsc);
        av[4] = (short)f2bf(v1.x * qsc); av[5] = (short)f2bf(v1.y * qsc);
        av[6] = (short)f2bf(v1.z * qsc); av[7] = (short)f2bf(v1.w * qsc);
        *(bf8*)&As[row][ac * 8] = av;
        int c = n0 + row;
        bf8 bv;
#pragma unroll
        for (int k = 0; k < 8; k++)
          bv[k] = (short)f2bf(w_in[(size_t)(kt * 64 + ac * 8 + k) * Cc + c]);
        *(bf8*)&Bs[row][ac * 8] = bv;
      }
      __syncthreads();
#pragma unroll
      for (int kk = 0; kk < 2; kk++) {
        bf8 af[2], bff[2];
#pragma unroll
        for (int i = 0; i < 2; i++) af[i] = *(const bf8*)&As[wm + i * 16 + lrow][kk * 32 + quad * 8];
#pragma unroll
        for (int j = 0; j < 2; j++) bff[j] = *(const bf8*)&Bs[wn + j * 16 + lrow][kk * 32 + quad * 8];
#pragma unroll
        for (int i = 0; i < 2; i++)
#pragma unroll
          for (int j = 0; j < 2; j++)
            acc[i][j] = __builtin_amdgcn_mfma_f32_16x16x32_bf16(af[i], bff[j], acc[i][j], 0, 0, 0);
      }
      __syncthreads();
    }
#pragma unroll
    for (int j = 0; j < 2; j++)
#pragma unroll
      for (int i = 0; i < 2; i++)
#pragma unroll
        for (int r = 0; r < 4; r++)
          wqin[(size_t)(m0 + wm + i * 16 + quad * 4 + r) * Cc + n0 + wn + j * 16 + lrow] =
              f2bf(acc[i][j][r]);
  } else {
    const int o = (bid - 2720) * 32 + (tid >> 3);
    const int k0 = (tid & 7) * 64;
    float s = 0.f;
#pragma unroll
    for (int i = 0; i < 16; i++) {
      float4 w = *(const float4*)(wq + (size_t)o * Ee + k0 + i * 4);
      float4 bb = *(const float4*)(b_in + k0 + i * 4);
      s += w.x * bb.x + w.y * bb.y + w.z * bb.z + w.w * bb.w;
    }
    s += __shfl_xor(s, 1);
    s += __shfl_xor(s, 2);
    s += __shfl_xor(s, 4);
    if ((tid & 7) == 0) bqinb[o] = (s + bq[o]) * qsc;
  }
}

// ---------------- Q-GEMM + KV-GEMM, one dispatch, A read as fp32 ----------------
// 128x128 tile, BK=64, waves 2x2. bid<256: Q = x.wqin^T + bqin -> Qb[8192,512].
// bid>=256: KV = ctx.[wk;wv]^T; cols<512 -> Kb[8192,512] (+bk); cols>=512 ->
// V written TRANSPOSED to Vt[b][h][d][s] (+bv) -- vtrans eliminated.
__global__ __launch_bounds__(256) void qkv(const float* __restrict__ x,
                                           const float* __restrict__ ctx,
                                           const unsigned short* __restrict__ wqin,
                                           const float* __restrict__ bqinb,
                                           const unsigned short* __restrict__ wkv,
                                           const float* __restrict__ bk,
                                           const float* __restrict__ bv,
                                           unsigned short* __restrict__ Qb,
                                           unsigned short* __restrict__ Kb,
                                           unsigned short* __restrict__ Vt) {
  __shared__ unsigned short As[128][72];
  __shared__ unsigned short Bs[128][72];
  const int bid = blockIdx.x, tid = threadIdx.x;
  const bool isQ = bid < 256;
  const int idx = isQ ? bid : bid - 256;
  const int m0 = (idx & 63) * 128;
  const int n0 = (idx >> 6) * 128;
  const int K = isQ ? 256 : 512;
  const float* A = isQ ? x : ctx;
  const unsigned short* Bt = isQ ? wqin : wkv;

  const int wave = tid >> 6, lane = tid & 63;
  const int lrow = lane & 15, quad = lane >> 4;
  const int wm = (wave >> 1) * 64, wn = (wave & 1) * 64;
  const int arow = tid >> 3, ac = tid & 7;

  f4 acc[4][4];
#pragma unroll
  for (int i = 0; i < 4; i++)
#pragma unroll
    for (int j = 0; j < 4; j++) {
      f4 z = {0.f, 0.f, 0.f, 0.f};
      acc[i][j] = z;
    }

  float4 ap0[4], ap1[4];
  bf8 bpre[4];
#pragma unroll
  for (int i = 0; i < 4; i++) {
    const float* src = A + (size_t)(m0 + arow + i * 32) * K + ac * 8;
    ap0[i] = *(const float4*)src;
    ap1[i] = *(const float4*)(src + 4);
    bpre[i] = *(const bf8*)(Bt + (size_t)(n0 + arow + i * 32) * K + ac * 8);
  }

  const int nkt = K >> 6;
  for (int kt = 0; kt < nkt; ++kt) {
#pragma unroll
    for (int i = 0; i < 4; i++) {
      *(bf8*)&As[arow + i * 32][ac * 8] = cvt8(ap0[i], ap1[i]);
      *(bf8*)&Bs[arow + i * 32][ac * 8] = bpre[i];
    }
    __syncthreads();
    if (kt + 1 < nkt) {
      int k0 = (kt + 1) << 6;
#pragma unroll
      for (int i = 0; i < 4; i++) {
        const float* src = A + (size_t)(m0 + arow + i * 32) * K + k0 + ac * 8;
        ap0[i] = *(const float4*)src;
        ap1[i] = *(const float4*)(src + 4);
        bpre[i] = *(const bf8*)(Bt + (size_t)(n0 + arow + i * 32) * K + k0 + ac * 8);
      }
    }
#pragma unroll
    for (int kk = 0; kk < 2; kk++) {
      bf8 af[4], bff[4];
#pragma unroll
      for (int i = 0; i < 4; i++)
        af[i] = *(const bf8*)&As[wm + i * 16 + lrow][kk * 32 + quad * 8];
#pragma unroll
      for (int j = 0; j < 4; j++)
        bff[j] = *(const bf8*)&Bs[wn + j * 16 + lrow][kk * 32 + quad * 8];
#pragma unroll
      for (int i = 0; i < 4; i++)
#pragma unroll
        for (int j = 0; j < 4; j++)
          acc[i][j] = __builtin_amdgcn_mfma_f32_16x16x32_bf16(af[i], bff[j],
                                                              acc[i][j], 0, 0, 0);
    }
    __syncthreads();
  }

  if (isQ) {
#pragma unroll
    for (int j = 0; j < 4; j++) {
      int col = n0 + wn + j * 16 + lrow;
      float bvv = bqinb[col];
#pragma unroll
      for (int i = 0; i < 4; i++)
#pragma unroll
        for (int r = 0; r < 4; r++)
          Qb[(size_t)(m0 + wm + i * 16 + quad * 4 + r) * Ee + col] =
              f2bf(acc[i][j][r] + bvv);
    }
  } else if (n0 < 512) {  // K half (uniform per block)
#pragma unroll
    for (int j = 0; j < 4; j++) {
      int col = n0 + wn + j * 16 + lrow;
      float bvv = bk[col];
#pragma unroll
      for (int i = 0; i < 4; i++)
#pragma unroll
        for (int r = 0; r < 4; r++)
          Kb[(size_t)(m0 + wm + i * 16 + quad * 4 + r) * Ee + col] =
              f2bf(acc[i][j][r] + bvv);
    }
  } else {  // V half -> transposed store
#pragma unroll
    for (int j = 0; j < 4; j++) {
      int d = n0 - 512 + wn + j * 16 + lrow;
      int h = d >> 6, dd = d & 63;
      float bvv = bv[d];
#pragma unroll
      for (int i = 0; i < 4; i++) {
        int tok = m0 + wm + i * 16 + quad * 4;  // 4 consecutive tokens
        int b = tok >> 11, sl = tok & 2047;
        ushort4 pk;
        pk.x = f2bf(acc[i][j][0] + bvv);
        pk.y = f2bf(acc[i][j][1] + bvv);
        pk.z = f2bf(acc[i][j][2] + bvv);
        pk.w = f2bf(acc[i][j][3] + bvv);
        *(ushort4*)(Vt + (size_t)((b * Hh + h) * 64 + dd) * Ssz + sl) = pk;
      }
    }
  }
}

// ---------------- GEMM: C[M,N] = A[M,K]*Bt[N,K]^T + bias (bf16 A) ----------------
template <bool OUT_BF16, int BM, int BN, int WGM>
__global__ __launch_bounds__(256) void gemm_bt(const unsigned short* __restrict__ A,
                                               const unsigned short* __restrict__ Bt,
                                               const float* __restrict__ bias0,
                                               void* __restrict__ Cout,
                                               int M, int N, int K) {
  constexpr int WGN = 4 / WGM;
  constexpr int MI = BM / (WGM * 16);
  constexpr int NJ = BN / (WGN * 16);
  constexpr int NA = BM / 32;
  constexpr int NB = BN / 32;
  __shared__ unsigned short As[BM][72];
  __shared__ unsigned short Bs[BN][72];
  const int tid = threadIdx.x;
  const int wave = tid >> 6, lane = tid & 63;
  const int lrow = lane & 15, quad = lane >> 4;
  const int wm = (wave / WGN) * (BM / WGM);
  const int wn = (wave % WGN) * (BN / WGN);
  const int m0 = blockIdx.x * BM, n0 = blockIdx.y * BN;
  const int arow = tid >> 3, ac = tid & 7;

  f4 acc[MI][NJ];
#pragma unroll
  for (int i = 0; i < MI; i++)
#pragma unroll
    for (int j = 0; j < NJ; j++) {
      f4 z = {0.f, 0.f, 0.f, 0.f};
      acc[i][j] = z;
    }

  bf8 apre[NA], bpre[NB];
#pragma unroll
  for (int i = 0; i < NA; i++)
    apre[i] = *(const bf8*)(A + (size_t)(m0 + arow + i * 32) * K + ac * 8);
#pragma unroll
  for (int i = 0; i < NB; i++)
    bpre[i] = *(const bf8*)(Bt + (size_t)(n0 + arow + i * 32) * K + ac * 8);

  const int nkt = K >> 6;
  for (int kt = 0; kt < nkt; ++kt) {
#pragma unroll
    for (int i = 0; i < NA; i++) *(bf8*)&As[arow + i * 32][ac * 8] = apre[i];
#pragma unroll
    for (int i = 0; i < NB; i++) *(bf8*)&Bs[arow + i * 32][ac * 8] = bpre[i];
    __syncthreads();
    if (kt + 1 < nkt) {
      int k0 = (kt + 1) << 6;
#pragma unroll
      for (int i = 0; i < NA; i++)
        apre[i] = *(const bf8*)(A + (size_t)(m0 + arow + i * 32) * K + k0 + ac * 8);
#pragma unroll
      for (int i = 0; i < NB; i++)
        bpre[i] = *(const bf8*)(Bt + (size_t)(n0 + arow + i * 32) * K + k0 + ac * 8);
    }
#pragma unroll
    for (int kk = 0; kk < 2; kk++) {
      bf8 af[MI], bff[NJ];
#pragma unroll
      for (int i = 0; i < MI; i++)
        af[i] = *(const bf8*)&As[wm + i * 16 + lrow][kk * 32 + quad * 8];
#pragma unroll
      for (int j = 0; j < NJ; j++)
        bff[j] = *(const bf8*)&Bs[wn + j * 16 + lrow][kk * 32 + quad * 8];
#pragma unroll
      for (int i = 0; i < MI; i++)
#pragma unroll
        for (int j = 0; j < NJ; j++)
          acc[i][j] = __builtin_amdgcn_mfma_f32_16x16x32_bf16(af[i], bff[j],
                                                              acc[i][j], 0, 0, 0);
    }
    __syncthreads();
  }

#pragma unroll
  for (int j = 0; j < NJ; j++) {
    int col = n0 + wn + j * 16 + lrow;
    float bvv = bias0 ? bias0[col] : 0.f;
#pragma unroll
    for (int i = 0; i < MI; i++) {
#pragma unroll
      for (int r = 0; r < 4; r++) {
        int row = m0 + wm + i * 16 + quad * 4 + r;
        float v = acc[i][j][r] + bvv;
        if (OUT_BF16)
          ((unsigned short*)Cout)[(size_t)row * N + col] = f2bf(v);
        else
          ((float*)Cout)[(size_t)row * N + col] = v;
      }
    }
  }
}

// ---------------- fused masked cross-attention ----------------
// Block = 256 t x full S; wave = 64 t (4 m-frags): K/V LDS frag reads amortized
// 4x vs r4. S^T = K.Q^T; P round-trip t-major (b64 write / b128 read).
// Double-buffered K/V (free: grid 256 = 1 block/CU). Denominator via MFMA
// ones-column on the same rounded P.
__global__ __launch_bounds__(256) void attn(const unsigned short* __restrict__ Q,
                                            const unsigned short* __restrict__ K,
                                            const unsigned short* __restrict__ Vt,
                                            const unsigned int* __restrict__ mp,
                                            unsigned short* __restrict__ O) {
  __shared__ unsigned short Ks[2][64][72];
  __shared__ unsigned short Vts[2][64][72];
  __shared__ unsigned short Ps[256][72];  // Q staging, then P (t-major)
  const int tid = threadIdx.x;
  const int wave = tid >> 6, lane = tid & 63;
  const int lrow = lane & 15, quad = lane >> 4;
  const int b = blockIdx.z, h = blockIdx.y, t0 = blockIdx.x * 256;
  const int arow = tid >> 3, ac = tid & 7;
  const int wm = wave * 64;

  // stage Q tile 256x64
#pragma unroll
  for (int i = 0; i < 8; i++) {
    int row = arow + i * 32;
    *(bf8*)&Ps[row][ac * 8] =
        *(const bf8*)(Q + (size_t)(b * Tt + t0 + row) * Ee + h * 64 + ac * 8);
  }
  __syncthreads();
  bf8 qf[4][2];
#pragma unroll
  for (int mi = 0; mi < 4; mi++) {
    qf[mi][0] = *(const bf8*)&Ps[wm + mi * 16 + lrow][quad * 8];
    qf[mi][1] = *(const bf8*)&Ps[wm + mi * 16 + lrow][32 + quad * 8];
  }

  f4 oacc[4][4];
  f4 dacc[4];
#pragma unroll
  for (int mi = 0; mi < 4; mi++) {
    f4 z = {0.f, 0.f, 0.f, 0.f};
    dacc[mi] = z;
#pragma unroll
    for (int j = 0; j < 4; j++) oacc[mi][j] = z;
  }
  bf8 ones;
#pragma unroll
  for (int k = 0; k < 8; k++) ones[k] = (short)0x3F80;  // bf16 1.0

  const unsigned short* Kbase = K + (size_t)b * Ssz * Ee + h * 64;
  const unsigned short* Vbase = Vt + (size_t)((b * Hh + h) * 64) * Ssz;
  const unsigned int* mrow[4];
#pragma unroll
  for (int mi = 0; mi < 4; mi++)
    mrow[mi] = mp + (size_t)(b * Tt + t0 + wm + mi * 16 + lrow) * 64;

  bf8 kreg[2], vreg[2];
#pragma unroll
  for (int i = 0; i < 2; i++) {
    int row = arow + i * 32;
    kreg[i] = *(const bf8*)(Kbase + (size_t)row * Ee + ac * 8);
    vreg[i] = *(const bf8*)(Vbase + (size_t)row * Ssz + ac * 8);
  }

  int buf = 0;
  for (int s0 = 0; s0 < Ssz; s0 += 64) {
#pragma unroll
    for (int i = 0; i < 2; i++) {
      int row = arow + i * 32;
      *(bf8*)&Ks[buf][row][ac * 8] = kreg[i];
      *(bf8*)&Vts[buf][row][ac * 8] = vreg[i];
    }
    __syncthreads();
    if (s0 + 64 < Ssz) {
#pragma unroll
      for (int i = 0; i < 2; i++) {
        int row = arow + i * 32;
        kreg[i] = *(const bf8*)(Kbase + (size_t)(s0 + 64 + row) * Ee + ac * 8);
        vreg[i] = *(const bf8*)(Vbase + (size_t)row * Ssz + s0 + 64 + ac * 8);
      }
    }
    uint2 mw[4];
#pragma unroll
    for (int mi = 0; mi < 4; mi++) mw[mi] = *(const uint2*)(mrow[mi] + (s0 >> 5));

    // scores: S^T frags (rows = s, cols = t)
#pragma unroll
    for (int sf = 0; sf < 4; sf++) {
      bf8 kf0 = *(const bf8*)&Ks[buf][sf * 16 + lrow][quad * 8];
      bf8 kf1 = *(const bf8*)&Ks[buf][sf * 16 + lrow][32 + quad * 8];
      f4 sa[4];
#pragma unroll
      for (int mi = 0; mi < 4; mi++) {
        f4 z = {0.f, 0.f, 0.f, 0.f};
        sa[mi] = z;
        sa[mi] = __builtin_amdgcn_mfma_f32_16x16x32_bf16(kf0, qf[mi][0], sa[mi], 0, 0, 0);
        sa[mi] = __builtin_amdgcn_mfma_f32_16x16x32_bf16(kf1, qf[mi][1], sa[mi], 0, 0, 0);
      }
#pragma unroll
      for (int mi = 0; mi < 4; mi++) {
        const unsigned int w = (sf >= 2) ? mw[mi].y : mw[mi].x;
        ushort4 pk;
#pragma unroll
        for (int r = 0; r < 4; r++) {
          const unsigned int bit = (sf & 1) * 16 + quad * 4 + r;
          float e = __builtin_amdgcn_exp2f(sa[mi][r]);
          float p = ((w >> bit) & 1u) ? 0.f : e;
          unsigned short pb = (unsigned short)(__float_as_uint(p) >> 16);
          if (r == 0) pk.x = pb;
          else if (r == 1) pk.y = pb;
          else if (r == 2) pk.z = pb;
          else pk.w = pb;
        }
        *(ushort4*)&Ps[wm + mi * 16 + lrow][sf * 16 + quad * 4] = pk;
      }
    }
    // PV + denominator
#pragma unroll
    for (int kk = 0; kk < 2; kk++) {
      bf8 pf[4];
#pragma unroll
      for (int mi = 0; mi < 4; mi++) {
        pf[mi] = *(const bf8*)&Ps[wm + mi * 16 + lrow][kk * 32 + quad * 8];
        dacc[mi] = __builtin_amdgcn_mfma_f32_16x16x32_bf16(pf[mi], ones, dacc[mi], 0, 0, 0);
      }
#pragma unroll
      for (int j = 0; j < 4; j++) {
        bf8 vf = *(const bf8*)&Vts[buf][j * 16 + lrow][kk * 32 + quad * 8];
#pragma unroll
        for (int mi = 0; mi < 4; mi++)
          oacc[mi][j] = __builtin_amdgcn_mfma_f32_16x16x32_bf16(pf[mi], vf, oacc[mi][j], 0, 0, 0);
      }
    }
    buf ^= 1;
  }

#pragma unroll
  for (int mi = 0; mi < 4; mi++) {
#pragma unroll
    for (int r = 0; r < 4; r++) {
      float inv = 1.0f / dacc[mi][r];
      int row = b * Tt + t0 + wm + mi * 16 + quad * 4 + r;
#pragma unroll
      for (int j = 0; j < 4; j++)
        O[(size_t)row * Ee + h * 64 + j * 16 + lrow] = f2bf(oacc[mi][j][r] * inv);
    }
  }
}

// ---------------- launcher ----------------
extern "C" void kernel_launch(void* const* d_in, const int* in_sizes, int n_in,
                              void* d_out, int out_size, void* d_ws, size_t ws_size,
                              hipStream_t stream) {
  const float* x    = (const float*)d_in[0];
  const float* ctx  = (const float*)d_in[1];
  const int*   mask = (const int*)d_in[2];
  const float* w_in = (const float*)d_in[3];
  const float* b_in = (const float*)d_in[4];
  const float* wq   = (const float*)d_in[5];
  const float* bq   = (const float*)d_in[6];
  const float* wk   = (const float*)d_in[7];
  const float* bk   = (const float*)d_in[8];
  const float* wv   = (const float*)d_in[9];
  const float* bv   = (const float*)d_in[10];
  const float* wo   = (const float*)d_in[11];
  const float* bo   = (const float*)d_in[12];

  const float qsc = 0.04419417382415922f * 1.4426950408889634f;  // E^-0.5 * log2(e)

  unsigned short* ws = (unsigned short*)d_ws;
  unsigned int*   maskp = (unsigned int*)ws;        // [4*2048*64] = 2MB
  unsigned short* wkvb  = ws + 1048576;             // [1024,512]
  unsigned short* wob   = ws + 1572864;             // [256,512]
  unsigned short* wqin  = ws + 1703936;             // [512,256]
  float*          bqinb = (float*)(ws + 1835008);   // [512]
  unsigned short* Qb    = ws + 1836032;             // [8192,512]
  unsigned short* Kb    = ws + 6030336;             // [8192,512]
  unsigned short* Vtb   = ws + 10224640;            // [32,64,2048]
  unsigned short* Ob    = ws + 14418944;            // [8192,512]

  prep<<<2736, 256, 0, stream>>>(mask, w_in, b_in, wq, bq, wk, wv, wo,
                                 maskp, wkvb, wob, wqin, bqinb, qsc);
  qkv<<<768, 256, 0, stream>>>(x, ctx, wqin, bqinb, wkvb, bk, bv, Qb, Kb, Vtb);
  attn<<<dim3(8, 8, 4), 256, 0, stream>>>(Qb, Kb, Vtb, maskp, Ob);
  gemm_bt<false, 64, 64, 2><<<dim3(128, 4), 256, 0, stream>>>(
      Ob, wob, bo, d_out, 8192, 256, 512);
}

// Round 7
// 237.550 us; speedup vs baseline: 1.1114x; 1.1114x over previous
//
#include <hip/hip_runtime.h>
#include <cstdint>
#include <cstddef>

#define Bb 4
#define Tt 2048
#define Ssz 2048
#define Cc 256
#define Ee 512
#define Hh 8

typedef short bf8 __attribute__((ext_vector_type(8)));
typedef float f4 __attribute__((ext_vector_type(4)));

__device__ __forceinline__ unsigned short f2bf(float x) {
  unsigned int u = __float_as_uint(x);
  u += 0x7fffu + ((u >> 16) & 1u);
  return (unsigned short)(u >> 16);
}

__device__ __forceinline__ bf8 cvt8(float4 a, float4 b) {
  bf8 r;
  r[0] = (short)f2bf(a.x); r[1] = (short)f2bf(a.y);
  r[2] = (short)f2bf(a.z); r[3] = (short)f2bf(a.w);
  r[4] = (short)f2bf(b.x); r[5] = (short)f2bf(b.y);
  r[6] = (short)f2bf(b.z); r[7] = (short)f2bf(b.w);
  return r;
}

// ---------------- prep: weight casts + wqin GEMM + bqin ----------------
// bid<512: wk/wv cast; <640: wo cast; <672: wqin; <688: bqin
__global__ __launch_bounds__(256) void prep(const float* __restrict__ w_in,
                                            const float* __restrict__ b_in,
                                            const float* __restrict__ wq,
                                            const float* __restrict__ bq,
                                            const float* __restrict__ wk,
                                            const float* __restrict__ wv,
                                            const float* __restrict__ wo,
                                            unsigned short* __restrict__ wkvb,
                                            unsigned short* __restrict__ wob,
                                            unsigned short* __restrict__ wqin,
                                            float* __restrict__ bqinb, float qsc) {
  __shared__ unsigned short sh[128][72];
  const int bid = blockIdx.x, tid = threadIdx.x;
  if (bid < 512) {
    int i = bid * 256 + tid;  // 0..131071
    const float* s = (i < 65536) ? wk : wv;
    int off = (i < 65536) ? i : i - 65536;
    float4 v = ((const float4*)s)[off];
    ushort4 o;
    o.x = f2bf(v.x); o.y = f2bf(v.y); o.z = f2bf(v.z); o.w = f2bf(v.w);
    ((ushort4*)wkvb)[i] = o;
  } else if (bid < 640) {
    int i = (bid - 512) * 256 + tid;  // 0..32767
    float4 v = ((const float4*)wo)[i];
    ushort4 o;
    o.x = f2bf(v.x); o.y = f2bf(v.y); o.z = f2bf(v.z); o.w = f2bf(v.w);
    ((ushort4*)wob)[i] = o;
  } else if (bid < 672) {
    // wqin[512,256] = (qsc*wq)[512,512] . w_in[512,256]
    const int idx = bid - 640;
    const int m0 = (idx & 7) * 64, n0 = (idx >> 3) * 64;
    unsigned short (*As)[72] = (unsigned short (*)[72]) & sh[0][0];
    unsigned short (*Bs)[72] = (unsigned short (*)[72]) & sh[64][0];
    const int wave = tid >> 6, lane = tid & 63;
    const int lrow = lane & 15, quad = lane >> 4;
    const int wm = (wave >> 1) * 32, wn = (wave & 1) * 32;
    const int arow = tid >> 3, ac = tid & 7;
    f4 acc[2][2];
#pragma unroll
    for (int i = 0; i < 2; i++)
#pragma unroll
      for (int j = 0; j < 2; j++) {
        f4 z = {0.f, 0.f, 0.f, 0.f};
        acc[i][j] = z;
      }
    for (int kt = 0; kt < 8; kt++) {
#pragma unroll
      for (int i = 0; i < 2; i++) {
        int row = arow + i * 32;
        const float* src = wq + (size_t)(m0 + row) * Ee + kt * 64 + ac * 8;
        float4 v0 = *(const float4*)src, v1 = *(const float4*)(src + 4);
        bf8 av;
        av[0] = (short)f2bf(v0.x * qsc); av[1] = (short)f2bf(v0.y * qsc);
        av[2] = (short)f2bf(v0.z * qsc); av[3] = (short)f2bf(v0.w * qsc);
        av[4] = (short)f2bf(v1.x * qsc); av[5] = (short)f2bf(v1.y * qsc);
        av[6] = (short)f2bf(v1.z * qsc); av[7] = (short)f2bf(v1.w * qsc);
        *(bf8*)&As[row][ac * 8] = av;
        int c = n0 + row;
        bf8 bv;
#pragma unroll
        for (int k = 0; k < 8; k++)
          bv[k] = (short)f2bf(w_in[(size_t)(kt * 64 + ac * 8 + k) * Cc + c]);
        *(bf8*)&Bs[row][ac * 8] = bv;
      }
      __syncthreads();
#pragma unroll
      for (int kk = 0; kk < 2; kk++) {
        bf8 af[2], bff[2];
#pragma unroll
        for (int i = 0; i < 2; i++) af[i] = *(const bf8*)&As[wm + i * 16 + lrow][kk * 32 + quad * 8];
#pragma unroll
        for (int j = 0; j < 2; j++) bff[j] = *(const bf8*)&Bs[wn + j * 16 + lrow][kk * 32 + quad * 8];
#pragma unroll
        for (int i = 0; i < 2; i++)
#pragma unroll
          for (int j = 0; j < 2; j++)
            acc[i][j] = __builtin_amdgcn_mfma_f32_16x16x32_bf16(af[i], bff[j], acc[i][j], 0, 0, 0);
      }
      __syncthreads();
    }
#pragma unroll
    for (int j = 0; j < 2; j++)
#pragma unroll
      for (int i = 0; i < 2; i++)
#pragma unroll
        for (int r = 0; r < 4; r++)
          wqin[(size_t)(m0 + wm + i * 16 + quad * 4 + r) * Cc + n0 + wn + j * 16 + lrow] =
              f2bf(acc[i][j][r]);
  } else {
    const int o = (bid - 672) * 32 + (tid >> 3);
    const int k0 = (tid & 7) * 64;
    float s = 0.f;
#pragma unroll
    for (int i = 0; i < 16; i++) {
      float4 w = *(const float4*)(wq + (size_t)o * Ee + k0 + i * 4);
      float4 bb = *(const float4*)(b_in + k0 + i * 4);
      s += w.x * bb.x + w.y * bb.y + w.z * bb.z + w.w * bb.w;
    }
    s += __shfl_xor(s, 1);
    s += __shfl_xor(s, 2);
    s += __shfl_xor(s, 4);
    if ((tid & 7) == 0) bqinb[o] = (s + bq[o]) * qsc;
  }
}

// ---------------- Q-GEMM + KV-GEMM + packmask, one dispatch ----------------
// bid<256: Q = x.wqin^T + bqin. bid in [256,768): KV = ctx.[wk;wv]^T (K half
// to Kb + bk; V half transposed to Vt + bv). bid>=768: mask bit-pack (its HBM
// read overlaps the compute-bound GEMM blocks).
__global__ __launch_bounds__(256) void qkv(const float* __restrict__ x,
                                           const float* __restrict__ ctx,
                                           const unsigned short* __restrict__ wqin,
                                           const float* __restrict__ bqinb,
                                           const unsigned short* __restrict__ wkv,
                                           const float* __restrict__ bk,
                                           const float* __restrict__ bv,
                                           unsigned short* __restrict__ Qb,
                                           unsigned short* __restrict__ Kb,
                                           unsigned short* __restrict__ Vt,
                                           const int* __restrict__ mask,
                                           unsigned int* __restrict__ mp) {
  __shared__ unsigned short As[128][72];
  __shared__ unsigned short Bs[128][72];
  const int bid = blockIdx.x, tid = threadIdx.x;
  if (bid >= 768) {
    int i = (bid - 768) * 256 + tid;  // 0..524287
    const int4* src = (const int4*)mask + (size_t)i * 8;
    unsigned int w = 0;
#pragma unroll
    for (int k = 0; k < 8; k++) {
      int4 v = src[k];
      w |= (unsigned int)(v.x != 0) << (k * 4);
      w |= (unsigned int)(v.y != 0) << (k * 4 + 1);
      w |= (unsigned int)(v.z != 0) << (k * 4 + 2);
      w |= (unsigned int)(v.w != 0) << (k * 4 + 3);
    }
    mp[i] = w;
    return;
  }
  const bool isQ = bid < 256;
  const int idx = isQ ? bid : bid - 256;
  const int m0 = (idx & 63) * 128;
  const int n0 = (idx >> 6) * 128;
  const int K = isQ ? 256 : 512;
  const float* A = isQ ? x : ctx;
  const unsigned short* Bt = isQ ? wqin : wkv;

  const int wave = tid >> 6, lane = tid & 63;
  const int lrow = lane & 15, quad = lane >> 4;
  const int wm = (wave >> 1) * 64, wn = (wave & 1) * 64;
  const int arow = tid >> 3, ac = tid & 7;

  f4 acc[4][4];
#pragma unroll
  for (int i = 0; i < 4; i++)
#pragma unroll
    for (int j = 0; j < 4; j++) {
      f4 z = {0.f, 0.f, 0.f, 0.f};
      acc[i][j] = z;
    }

  float4 ap0[4], ap1[4];
  bf8 bpre[4];
#pragma unroll
  for (int i = 0; i < 4; i++) {
    const float* src = A + (size_t)(m0 + arow + i * 32) * K + ac * 8;
    ap0[i] = *(const float4*)src;
    ap1[i] = *(const float4*)(src + 4);
    bpre[i] = *(const bf8*)(Bt + (size_t)(n0 + arow + i * 32) * K + ac * 8);
  }

  const int nkt = K >> 6;
  for (int kt = 0; kt < nkt; ++kt) {
#pragma unroll
    for (int i = 0; i < 4; i++) {
      *(bf8*)&As[arow + i * 32][ac * 8] = cvt8(ap0[i], ap1[i]);
      *(bf8*)&Bs[arow + i * 32][ac * 8] = bpre[i];
    }
    __syncthreads();
    if (kt + 1 < nkt) {
      int k0 = (kt + 1) << 6;
#pragma unroll
      for (int i = 0; i < 4; i++) {
        const float* src = A + (size_t)(m0 + arow + i * 32) * K + k0 + ac * 8;
        ap0[i] = *(const float4*)src;
        ap1[i] = *(const float4*)(src + 4);
        bpre[i] = *(const bf8*)(Bt + (size_t)(n0 + arow + i * 32) * K + k0 + ac * 8);
      }
    }
#pragma unroll
    for (int kk = 0; kk < 2; kk++) {
      bf8 af[4], bff[4];
#pragma unroll
      for (int i = 0; i < 4; i++)
        af[i] = *(const bf8*)&As[wm + i * 16 + lrow][kk * 32 + quad * 8];
#pragma unroll
      for (int j = 0; j < 4; j++)
        bff[j] = *(const bf8*)&Bs[wn + j * 16 + lrow][kk * 32 + quad * 8];
#pragma unroll
      for (int i = 0; i < 4; i++)
#pragma unroll
        for (int j = 0; j < 4; j++)
          acc[i][j] = __builtin_amdgcn_mfma_f32_16x16x32_bf16(af[i], bff[j],
                                                              acc[i][j], 0, 0, 0);
    }
    __syncthreads();
  }

  if (isQ) {
#pragma unroll
    for (int j = 0; j < 4; j++) {
      int col = n0 + wn + j * 16 + lrow;
      float bvv = bqinb[col];
#pragma unroll
      for (int i = 0; i < 4; i++)
#pragma unroll
        for (int r = 0; r < 4; r++)
          Qb[(size_t)(m0 + wm + i * 16 + quad * 4 + r) * Ee + col] =
              f2bf(acc[i][j][r] + bvv);
    }
  } else if (n0 < 512) {  // K half (uniform per block)
#pragma unroll
    for (int j = 0; j < 4; j++) {
      int col = n0 + wn + j * 16 + lrow;
      float bvv = bk[col];
#pragma unroll
      for (int i = 0; i < 4; i++)
#pragma unroll
        for (int r = 0; r < 4; r++)
          Kb[(size_t)(m0 + wm + i * 16 + quad * 4 + r) * Ee + col] =
              f2bf(acc[i][j][r] + bvv);
    }
  } else {  // V half -> transposed store
#pragma unroll
    for (int j = 0; j < 4; j++) {
      int d = n0 - 512 + wn + j * 16 + lrow;
      int h = d >> 6, dd = d & 63;
      float bvv = bv[d];
#pragma unroll
      for (int i = 0; i < 4; i++) {
        int tok = m0 + wm + i * 16 + quad * 4;  // 4 consecutive tokens
        int b = tok >> 11, sl = tok & 2047;
        ushort4 pk;
        pk.x = f2bf(acc[i][j][0] + bvv);
        pk.y = f2bf(acc[i][j][1] + bvv);
        pk.z = f2bf(acc[i][j][2] + bvv);
        pk.w = f2bf(acc[i][j][3] + bvv);
        *(ushort4*)(Vt + (size_t)((b * Hh + h) * 64 + dd) * Ssz + sl) = pk;
      }
    }
  }
}

// ---------------- GEMM: C[M,N] = A[M,K]*Bt[N,K]^T + bias (bf16 A) ----------------
template <bool OUT_BF16, int BM, int BN, int WGM>
__global__ __launch_bounds__(256) void gemm_bt(const unsigned short* __restrict__ A,
                                               const unsigned short* __restrict__ Bt,
                                               const float* __restrict__ bias0,
                                               void* __restrict__ Cout,
                                               int M, int N, int K) {
  constexpr int WGN = 4 / WGM;
  constexpr int MI = BM / (WGM * 16);
  constexpr int NJ = BN / (WGN * 16);
  constexpr int NA = BM / 32;
  constexpr int NB = BN / 32;
  __shared__ unsigned short As[BM][72];
  __shared__ unsigned short Bs[BN][72];
  const int tid = threadIdx.x;
  const int wave = tid >> 6, lane = tid & 63;
  const int lrow = lane & 15, quad = lane >> 4;
  const int wm = (wave / WGN) * (BM / WGM);
  const int wn = (wave % WGN) * (BN / WGN);
  const int m0 = blockIdx.x * BM, n0 = blockIdx.y * BN;
  const int arow = tid >> 3, ac = tid & 7;

  f4 acc[MI][NJ];
#pragma unroll
  for (int i = 0; i < MI; i++)
#pragma unroll
    for (int j = 0; j < NJ; j++) {
      f4 z = {0.f, 0.f, 0.f, 0.f};
      acc[i][j] = z;
    }

  bf8 apre[NA], bpre[NB];
#pragma unroll
  for (int i = 0; i < NA; i++)
    apre[i] = *(const bf8*)(A + (size_t)(m0 + arow + i * 32) * K + ac * 8);
#pragma unroll
  for (int i = 0; i < NB; i++)
    bpre[i] = *(const bf8*)(Bt + (size_t)(n0 + arow + i * 32) * K + ac * 8);

  const int nkt = K >> 6;
  for (int kt = 0; kt < nkt; ++kt) {
#pragma unroll
    for (int i = 0; i < NA; i++) *(bf8*)&As[arow + i * 32][ac * 8] = apre[i];
#pragma unroll
    for (int i = 0; i < NB; i++) *(bf8*)&Bs[arow + i * 32][ac * 8] = bpre[i];
    __syncthreads();
    if (kt + 1 < nkt) {
      int k0 = (kt + 1) << 6;
#pragma unroll
      for (int i = 0; i < NA; i++)
        apre[i] = *(const bf8*)(A + (size_t)(m0 + arow + i * 32) * K + k0 + ac * 8);
#pragma unroll
      for (int i = 0; i < NB; i++)
        bpre[i] = *(const bf8*)(Bt + (size_t)(n0 + arow + i * 32) * K + k0 + ac * 8);
    }
#pragma unroll
    for (int kk = 0; kk < 2; kk++) {
      bf8 af[MI], bff[NJ];
#pragma unroll
      for (int i = 0; i < MI; i++)
        af[i] = *(const bf8*)&As[wm + i * 16 + lrow][kk * 32 + quad * 8];
#pragma unroll
      for (int j = 0; j < NJ; j++)
        bff[j] = *(const bf8*)&Bs[wn + j * 16 + lrow][kk * 32 + quad * 8];
#pragma unroll
      for (int i = 0; i < MI; i++)
#pragma unroll
        for (int j = 0; j < NJ; j++)
          acc[i][j] = __builtin_amdgcn_mfma_f32_16x16x32_bf16(af[i], bff[j],
                                                              acc[i][j], 0, 0, 0);
    }
    __syncthreads();
  }

#pragma unroll
  for (int j = 0; j < NJ; j++) {
    int col = n0 + wn + j * 16 + lrow;
    float bvv = bias0 ? bias0[col] : 0.f;
#pragma unroll
    for (int i = 0; i < MI; i++) {
#pragma unroll
      for (int r = 0; r < 4; r++) {
        int row = m0 + wm + i * 16 + quad * 4 + r;
        float v = acc[i][j][r] + bvv;
        if (OUT_BF16)
          ((unsigned short*)Cout)[(size_t)row * N + col] = f2bf(v);
        else
          ((float*)Cout)[(size_t)row * N + col] = v;
      }
    }
  }
}

// ---------------- fused masked cross-attention ----------------
// Flat grid 512, XCD-swizzled: bh = bid&31 (constant mod 8 -> one XCD per bh,
// K/Vt stay L2-resident), t0 = (bid>>5)*128. Block = 128 t x full S; wave =
// 32 t. S^T = K.Q^T (vectorized P round-trip: b64 write, b128 read).
// Single-buffered K/V, 2-barrier pipeline -> LDS 36.9 KB -> 4 blocks/CU.
// Denominator via MFMA ones-column on the same rounded P.
__global__ __launch_bounds__(256) void attn(const unsigned short* __restrict__ Q,
                                            const unsigned short* __restrict__ K,
                                            const unsigned short* __restrict__ Vt,
                                            const unsigned int* __restrict__ mp,
                                            unsigned short* __restrict__ O) {
  __shared__ unsigned short Ks[64][72];
  __shared__ unsigned short Vts[64][72];
  __shared__ unsigned short Ps[128][72];  // Q staging, then P (t-major)
  const int tid = threadIdx.x;
  const int wave = tid >> 6, lane = tid & 63;
  const int lrow = lane & 15, quad = lane >> 4;
  const int bid = blockIdx.x;
  const int bh = bid & 31, b = bh >> 3, h = bh & 7;
  const int t0 = (bid >> 5) * 128;
  const int arow = tid >> 3, ac = tid & 7;
  const int wm = wave * 32;

  // stage Q tile 128x64 through Ps
#pragma unroll
  for (int i = 0; i < 4; i++) {
    int row = arow + i * 32;
    *(bf8*)&Ps[row][ac * 8] =
        *(const bf8*)(Q + (size_t)(b * Tt + t0 + row) * Ee + h * 64 + ac * 8);
  }
  __syncthreads();
  bf8 qf[2][2];  // B-operand frags (n = t)
#pragma unroll
  for (int mi = 0; mi < 2; mi++) {
    qf[mi][0] = *(const bf8*)&Ps[wm + mi * 16 + lrow][quad * 8];
    qf[mi][1] = *(const bf8*)&Ps[wm + mi * 16 + lrow][32 + quad * 8];
  }

  f4 oacc[2][4];
  f4 dacc[2];
#pragma unroll
  for (int mi = 0; mi < 2; mi++) {
    f4 z = {0.f, 0.f, 0.f, 0.f};
    dacc[mi] = z;
#pragma unroll
    for (int j = 0; j < 4; j++) oacc[mi][j] = z;
  }
  bf8 ones;
#pragma unroll
  for (int k = 0; k < 8; k++) ones[k] = (short)0x3F80;  // bf16 1.0

  const unsigned short* Kbase = K + (size_t)b * Ssz * Ee + h * 64;
  const unsigned short* Vbase = Vt + (size_t)((b * Hh + h) * 64) * Ssz;
  const unsigned int* mrow0 = mp + (size_t)(b * Tt + t0 + wm + lrow) * 64;
  const unsigned int* mrow1 = mp + (size_t)(b * Tt + t0 + wm + 16 + lrow) * 64;

  bf8 kreg[2], vreg[2];
#pragma unroll
  for (int i = 0; i < 2; i++) {
    int row = arow + i * 32;
    kreg[i] = *(const bf8*)(Kbase + (size_t)row * Ee + ac * 8);
    vreg[i] = *(const bf8*)(Vbase + (size_t)row * Ssz + ac * 8);
  }

  for (int s0 = 0; s0 < Ssz; s0 += 64) {
    __syncthreads();  // prior iteration's Ks/Vts reads complete
#pragma unroll
    for (int i = 0; i < 2; i++) {
      int row = arow + i * 32;
      *(bf8*)&Ks[row][ac * 8] = kreg[i];
      *(bf8*)&Vts[row][ac * 8] = vreg[i];
    }
    __syncthreads();
    if (s0 + 64 < Ssz) {
#pragma unroll
      for (int i = 0; i < 2; i++) {
        int row = arow + i * 32;
        kreg[i] = *(const bf8*)(Kbase + (size_t)(s0 + 64 + row) * Ee + ac * 8);
        vreg[i] = *(const bf8*)(Vbase + (size_t)row * Ssz + s0 + 64 + ac * 8);
      }
    }
    const uint2 mw0 = *(const uint2*)(mrow0 + (s0 >> 5));
    const uint2 mw1 = *(const uint2*)(mrow1 + (s0 >> 5));

    // scores: S^T frags (rows = s, cols = t)
#pragma unroll
    for (int sf = 0; sf < 4; sf++) {
      bf8 kf0 = *(const bf8*)&Ks[sf * 16 + lrow][quad * 8];
      bf8 kf1 = *(const bf8*)&Ks[sf * 16 + lrow][32 + quad * 8];
      f4 sa[2];
      f4 z = {0.f, 0.f, 0.f, 0.f};
      sa[0] = z; sa[1] = z;
      sa[0] = __builtin_amdgcn_mfma_f32_16x16x32_bf16(kf0, qf[0][0], sa[0], 0, 0, 0);
      sa[0] = __builtin_amdgcn_mfma_f32_16x16x32_bf16(kf1, qf[0][1], sa[0], 0, 0, 0);
      sa[1] = __builtin_amdgcn_mfma_f32_16x16x32_bf16(kf0, qf[1][0], sa[1], 0, 0, 0);
      sa[1] = __builtin_amdgcn_mfma_f32_16x16x32_bf16(kf1, qf[1][1], sa[1], 0, 0, 0);
#pragma unroll
      for (int mi = 0; mi < 2; mi++) {
        const uint2 mw = mi ? mw1 : mw0;
        const unsigned int w = (sf >= 2) ? mw.y : mw.x;  // static per sf
        ushort4 pk;
#pragma unroll
        for (int r = 0; r < 4; r++) {
          const unsigned int bit = (sf & 1) * 16 + quad * 4 + r;
          float e = __builtin_amdgcn_exp2f(sa[mi][r]);
          float p = ((w >> bit) & 1u) ? 0.f : e;
          unsigned short pb = (unsigned short)(__float_as_uint(p) >> 16);
          if (r == 0) pk.x = pb;
          else if (r == 1) pk.y = pb;
          else if (r == 2) pk.z = pb;
          else pk.w = pb;
        }
        *(ushort4*)&Ps[wm + mi * 16 + lrow][sf * 16 + quad * 4] = pk;  // b64
      }
    }
    // PV + denominator
#pragma unroll
    for (int kk = 0; kk < 2; kk++) {
      bf8 pf[2];
#pragma unroll
      for (int mi = 0; mi < 2; mi++) {
        pf[mi] = *(const bf8*)&Ps[wm + mi * 16 + lrow][kk * 32 + quad * 8];  // b128
        dacc[mi] = __builtin_amdgcn_mfma_f32_16x16x32_bf16(pf[mi], ones, dacc[mi], 0, 0, 0);
      }
#pragma unroll
      for (int j = 0; j < 4; j++) {
        bf8 vf = *(const bf8*)&Vts[j * 16 + lrow][kk * 32 + quad * 8];
#pragma unroll
        for (int mi = 0; mi < 2; mi++)
          oacc[mi][j] = __builtin_amdgcn_mfma_f32_16x16x32_bf16(pf[mi], vf, oacc[mi][j], 0, 0, 0);
      }
    }
  }

#pragma unroll
  for (int mi = 0; mi < 2; mi++) {
#pragma unroll
    for (int r = 0; r < 4; r++) {
      float inv = 1.0f / dacc[mi][r];
      int row = b * Tt + t0 + wm + mi * 16 + quad * 4 + r;
#pragma unroll
      for (int j = 0; j < 4; j++)
        O[(size_t)row * Ee + h * 64 + j * 16 + lrow] = f2bf(oacc[mi][j][r] * inv);
    }
  }
}

// ---------------- launcher ----------------
extern "C" void kernel_launch(void* const* d_in, const int* in_sizes, int n_in,
                              void* d_out, int out_size, void* d_ws, size_t ws_size,
                              hipStream_t stream) {
  const float* x    = (const float*)d_in[0];
  const float* ctx  = (const float*)d_in[1];
  const int*   mask = (const int*)d_in[2];
  const float* w_in = (const float*)d_in[3];
  const float* b_in = (const float*)d_in[4];
  const float* wq   = (const float*)d_in[5];
  const float* bq   = (const float*)d_in[6];
  const float* wk   = (const float*)d_in[7];
  const float* bk   = (const float*)d_in[8];
  const float* wv   = (const float*)d_in[9];
  const float* bv   = (const float*)d_in[10];
  const float* wo   = (const float*)d_in[11];
  const float* bo   = (const float*)d_in[12];

  const float qsc = 0.04419417382415922f * 1.4426950408889634f;  // E^-0.5 * log2(e)

  unsigned short* ws = (unsigned short*)d_ws;
  unsigned int*   maskp = (unsigned int*)ws;        // [4*2048*64] = 2MB
  unsigned short* wkvb  = ws + 1048576;             // [1024,512]
  unsigned short* wob   = ws + 1572864;             // [256,512]
  unsigned short* wqin  = ws + 1703936;             // [512,256]
  float*          bqinb = (float*)(ws + 1835008);   // [512]
  unsigned short* Qb    = ws + 1836032;             // [8192,512]
  unsigned short* Kb    = ws + 6030336;             // [8192,512]
  unsigned short* Vtb   = ws + 10224640;            // [32,64,2048]
  unsigned short* Ob    = ws + 14418944;            // [8192,512]

  prep<<<688, 256, 0, stream>>>(w_in, b_in, wq, bq, wk, wv, wo,
                                wkvb, wob, wqin, bqinb, qsc);
  qkv<<<2816, 256, 0, stream>>>(x, ctx, wqin, bqinb, wkvb, bk, bv, Qb, Kb, Vtb,
                                mask, maskp);
  attn<<<512, 256, 0, stream>>>(Qb, Kb, Vtb, maskp, Ob);
  gemm_bt<false, 64, 64, 2><<<dim3(128, 4), 256, 0, stream>>>(
      Ob, wob, bo, d_out, 8192, 256, 512);
}